// Round 1
// baseline (408.517 us; speedup 1.0000x reference)
//
#include <hip/hip_runtime.h>

namespace {

constexpr int kN  = 50000;
constexpr int kE  = 200000;
constexpr int kC  = 32;
constexpr int kND = 75;
constexpr int kED = 12;
constexpr int kL  = 3;
constexpr int kG  = 500;
constexpr int kH  = 5;
constexpr float kEps = 1e-5f;

// h = leaky(x @ lin_W + lin_b)   [N,75]@[75,32]
__global__ __launch_bounds__(256) void init_h(
    const float* __restrict__ x, const float* __restrict__ W,
    const float* __restrict__ b, float* __restrict__ h)
{
    __shared__ float sW[kND * kC];
    __shared__ float sb[kC];
    int t = threadIdx.x;
    for (int i = t; i < kND * kC; i += 256) sW[i] = W[i];
    if (t < kC) sb[t] = b[t];
    __syncthreads();
    int c = t & 31;
    int n = blockIdx.x * 8 + (t >> 5);
    if (n >= kN) return;
    const float* xr = x + n * kND;
    float acc = sb[c];
    #pragma unroll 5
    for (int f = 0; f < kND; ++f) acc = fmaf(xr[f], sW[f * kC + c], acc);
    h[n * kC + c] = acc > 0.f ? acc : 0.01f * acc;
}

// Per node: Y[n][k][:] = h[n] @ M_k (k=0..4), Y[n][5][:] = h[n] @ B2mat,
// obuf[n][:] = h[n] @ rootW + conv_b.   Block = 32 nodes, 4 nodes/thread
// so each LDS matrix value is reused 4x in registers.
__global__ __launch_bounds__(256) void y_root(
    const float* __restrict__ h,
    const float* __restrict__ W2,    // [5*1024] this layer
    const float* __restrict__ b2,    // [1024]
    const float* __restrict__ rootW, // [1024]
    const float* __restrict__ convb, // [32]
    float* __restrict__ Y, float* __restrict__ obuf,
    float* __restrict__ stats)
{
    __shared__ float sM[7 * 1024];
    __shared__ float sh[32 * kC];
    __shared__ float scb[kC];
    int t = threadIdx.x;
    if (blockIdx.x == 0 && t < 64) stats[t] = 0.f;   // zero BN stats for this layer
    for (int i = t; i < 5 * 1024; i += 256) sM[i] = W2[i];
    for (int i = t; i < 1024; i += 256) {
        sM[5 * 1024 + i] = b2[i];
        sM[6 * 1024 + i] = rootW[i];
    }
    if (t < kC) scb[t] = convb[t];

    int base = blockIdx.x * 32;
    #pragma unroll
    for (int j = 0; j < 4; ++j) {
        int idx = t + j * 256;
        int n = base + (idx >> 5);
        sh[idx] = (n < kN) ? h[n * kC + (idx & 31)] : 0.f;
    }
    __syncthreads();

    int d = t & 31;
    int li = t >> 5;   // node sub-group 0..7, nodes li*4 .. li*4+3
    float acc[7][4];
    #pragma unroll
    for (int k = 0; k < 7; ++k)
        #pragma unroll
        for (int j = 0; j < 4; ++j) acc[k][j] = 0.f;

    #pragma unroll 4
    for (int c = 0; c < kC; ++c) {
        int off = c * 32 + d;
        float m0 = sM[0 * 1024 + off];
        float m1 = sM[1 * 1024 + off];
        float m2 = sM[2 * 1024 + off];
        float m3 = sM[3 * 1024 + off];
        float m4 = sM[4 * 1024 + off];
        float m5 = sM[5 * 1024 + off];
        float m6 = sM[6 * 1024 + off];
        #pragma unroll
        for (int j = 0; j < 4; ++j) {
            float hc = sh[(li * 4 + j) * kC + c];
            acc[0][j] = fmaf(hc, m0, acc[0][j]);
            acc[1][j] = fmaf(hc, m1, acc[1][j]);
            acc[2][j] = fmaf(hc, m2, acc[2][j]);
            acc[3][j] = fmaf(hc, m3, acc[3][j]);
            acc[4][j] = fmaf(hc, m4, acc[4][j]);
            acc[5][j] = fmaf(hc, m5, acc[5][j]);
            acc[6][j] = fmaf(hc, m6, acc[6][j]);
        }
    }
    #pragma unroll
    for (int j = 0; j < 4; ++j) {
        int n = base + li * 4 + j;
        if (n >= kN) continue;
        float* yr = Y + (size_t)n * 192;
        yr[0 * 32 + d] = acc[0][j];
        yr[1 * 32 + d] = acc[1][j];
        yr[2 * 32 + d] = acc[2][j];
        yr[3 * 32 + d] = acc[3][j];
        yr[4 * 32 + d] = acc[4][j];
        yr[5 * 32 + d] = acc[5][j];
        obuf[n * kC + d] = acc[6][j] + scb[d];
    }
}

// Per edge: hid = relu(ea@W1+b1) (5 vals, lanes 0..4 of each 32-lane group),
// msg = Y[src][5] + sum_k hid_k * Y[src][k], atomicAdd into obuf[dst].
__global__ __launch_bounds__(256) void edge_msg(
    const int* __restrict__ ei_src, const int* __restrict__ ei_dst,
    const float* __restrict__ ea,
    const float* __restrict__ W1, const float* __restrict__ b1,
    const float* __restrict__ Y, float* __restrict__ obuf)
{
    __shared__ float sW1[kED * kH];
    __shared__ float sb1[kH];
    int t = threadIdx.x;
    if (t < kED * kH) sW1[t] = W1[t];
    if (t < kH) sb1[t] = b1[t];
    __syncthreads();
    int gid = blockIdx.x * 256 + t;
    int e = gid >> 5;
    int d = gid & 31;
    if (e >= kE) return;
    int src = ei_src[e];
    int dst = ei_dst[e];
    float hv = 0.f;
    if (d < kH) {
        const float* er = ea + e * kED;
        float a = sb1[d];
        #pragma unroll
        for (int j = 0; j < kED; ++j) a = fmaf(er[j], sW1[j * kH + d], a);
        hv = a > 0.f ? a : 0.f;
    }
    float h0 = __shfl(hv, 0, 32);
    float h1 = __shfl(hv, 1, 32);
    float h2 = __shfl(hv, 2, 32);
    float h3 = __shfl(hv, 3, 32);
    float h4 = __shfl(hv, 4, 32);
    const float* yr = Y + (size_t)src * 192;
    float m = yr[5 * 32 + d];
    m = fmaf(h0, yr[0 * 32 + d], m);
    m = fmaf(h1, yr[1 * 32 + d], m);
    m = fmaf(h2, yr[2 * 32 + d], m);
    m = fmaf(h3, yr[3 * 32 + d], m);
    m = fmaf(h4, yr[4 * 32 + d], m);
    atomicAdd(&obuf[dst * kC + d], m);
}

// Per-channel sum & sumsq over all N nodes -> stats[0..31]=sum, [32..63]=sumsq
__global__ __launch_bounds__(256) void bn_reduce(
    const float* __restrict__ obuf, float* __restrict__ stats)
{
    __shared__ float ls[256];
    __shared__ float lq[256];
    int t = threadIdx.x;
    int c = t & 31;
    int row = t >> 5;
    float s = 0.f, q = 0.f;
    for (int n = blockIdx.x * 8 + row; n < kN; n += gridDim.x * 8) {
        float v = obuf[n * kC + c];
        s += v; q += v * v;
    }
    ls[t] = s; lq[t] = q;
    __syncthreads();
    if (t < 128) { ls[t] += ls[t + 128]; lq[t] += lq[t + 128]; }
    __syncthreads();
    if (t < 64) { ls[t] += ls[t + 64]; lq[t] += lq[t + 64]; }
    __syncthreads();
    if (t < 32) {
        atomicAdd(&stats[t], ls[t] + ls[t + 32]);
        atomicAdd(&stats[32 + t], lq[t] + lq[t + 32]);
    }
}

template <bool LEAKY, bool INIT_OUT>
__global__ __launch_bounds__(256) void bn_norm(
    const float* __restrict__ obuf, const float* __restrict__ stats,
    const float* __restrict__ g, const float* __restrict__ b,
    float* __restrict__ h, float* __restrict__ out,
    const float* __restrict__ pred_b)
{
    int idx = blockIdx.x * 256 + threadIdx.x;
    if (INIT_OUT) {
        if (idx < kG) out[idx] = pred_b[0];   // next kernel (readout) atomics on top
    }
    if (idx < kN * kC) {
        int c = idx & 31;
        float mu = stats[c] * (1.f / kN);
        float var = stats[32 + c] * (1.f / kN) - mu * mu;
        float inv = rsqrtf(var + kEps);
        float v = (obuf[idx] - mu) * inv * g[c] + b[c];
        if (LEAKY) v = v > 0.f ? v : 0.01f * v;
        h[idx] = v;
    }
}

// out[batch[n]] += h[n] . pred_W   (prediction head is linear, so it commutes
// with segment_sum)
__global__ __launch_bounds__(256) void readout(
    const float* __restrict__ h, const int* __restrict__ batch,
    const float* __restrict__ predW, float* __restrict__ out)
{
    int idx = blockIdx.x * 256 + threadIdx.x;
    int n = idx >> 5;
    int c = idx & 31;
    if (n >= kN) return;
    float v = h[idx] * predW[c];
    #pragma unroll
    for (int off = 16; off > 0; off >>= 1) v += __shfl_down(v, off, 32);
    if (c == 0) atomicAdd(&out[batch[n]], v);
}

} // namespace

extern "C" void kernel_launch(void* const* d_in, const int* in_sizes, int n_in,
                              void* d_out, int out_size, void* d_ws, size_t ws_size,
                              hipStream_t stream)
{
    const float* x      = (const float*)d_in[0];
    const int*   ei     = (const int*)d_in[1];
    const float* ea     = (const float*)d_in[2];
    const int*   batch  = (const int*)d_in[3];
    const float* lin_W  = (const float*)d_in[4];
    const float* lin_b  = (const float*)d_in[5];
    const float* mes_W1 = (const float*)d_in[6];
    const float* mes_b1 = (const float*)d_in[7];
    const float* mes_W2 = (const float*)d_in[8];
    const float* mes_b2 = (const float*)d_in[9];
    const float* root_W = (const float*)d_in[10];
    const float* conv_b = (const float*)d_in[11];
    const float* bn_g   = (const float*)d_in[12];
    const float* bn_b   = (const float*)d_in[13];
    const float* pred_W = (const float*)d_in[14];
    const float* pred_b = (const float*)d_in[15];
    float* out = (float*)d_out;

    // workspace layout (floats): hbuf[N*C] | obuf[N*C] | Y[N*6*C] | stats[64]
    float* hbuf  = (float*)d_ws;
    float* obuf  = hbuf + (size_t)kN * kC;
    float* Y     = obuf + (size_t)kN * kC;
    float* stats = Y + (size_t)kN * 6 * kC;

    init_h<<<(kN + 7) / 8, 256, 0, stream>>>(x, lin_W, lin_b, hbuf);

    for (int l = 0; l < kL; ++l) {
        y_root<<<(kN + 31) / 32, 256, 0, stream>>>(
            hbuf, mes_W2 + l * kH * kC * kC, mes_b2 + l * kC * kC,
            root_W + l * kC * kC, conv_b + l * kC, Y, obuf, stats);
        edge_msg<<<(kE * 32 + 255) / 256, 256, 0, stream>>>(
            ei, ei + kE, ea, mes_W1 + l * kED * kH, mes_b1 + l * kH, Y, obuf);
        bn_reduce<<<512, 256, 0, stream>>>(obuf, stats);
        int nb = (kN * kC + 255) / 256;
        if (l < kL - 1)
            bn_norm<true, false><<<nb, 256, 0, stream>>>(
                obuf, stats, bn_g + l * kC, bn_b + l * kC, hbuf, out, pred_b);
        else
            bn_norm<false, true><<<nb, 256, 0, stream>>>(
                obuf, stats, bn_g + l * kC, bn_b + l * kC, hbuf, out, pred_b);
    }

    readout<<<(kN * kC + 255) / 256, 256, 0, stream>>>(hbuf, batch, pred_W, out);
}

// Round 2
// 343.089 us; speedup vs baseline: 1.1907x; 1.1907x over previous
//
#include <hip/hip_runtime.h>

namespace {

constexpr int kN  = 50000;
constexpr int kE  = 200000;
constexpr int kC  = 32;
constexpr int kND = 75;
constexpr int kED = 12;
constexpr int kL  = 3;
constexpr int kG  = 500;
constexpr int kH  = 5;
constexpr float kEps = 1e-5f;

// h = leaky(x @ lin_W + lin_b)   [N,75]@[75,32]
__global__ __launch_bounds__(256) void init_h(
    const float* __restrict__ x, const float* __restrict__ W,
    const float* __restrict__ b, float* __restrict__ h)
{
    __shared__ float sW[kND * kC];
    __shared__ float sb[kC];
    int t = threadIdx.x;
    for (int i = t; i < kND * kC; i += 256) sW[i] = W[i];
    if (t < kC) sb[t] = b[t];
    __syncthreads();
    int c = t & 31;
    int n = blockIdx.x * 8 + (t >> 5);
    if (n >= kN) return;
    const float* xr = x + n * kND;
    float acc = sb[c];
    #pragma unroll 5
    for (int f = 0; f < kND; ++f) acc = fmaf(xr[f], sW[f * kC + c], acc);
    h[n * kC + c] = acc > 0.f ? acc : 0.01f * acc;
}

// Per node: Y[n][k][:] = h[n] @ M_k (k=0..4), Y[n][5][:] = h[n] @ B2mat,
// obuf[n][:] = h[n] @ rootW + conv_b.   Block = 32 nodes, 4 nodes/thread.
__global__ __launch_bounds__(256) void y_root(
    const float* __restrict__ h,
    const float* __restrict__ W2,    // [5*1024] this layer
    const float* __restrict__ b2,    // [1024]
    const float* __restrict__ rootW, // [1024]
    const float* __restrict__ convb, // [32]
    float* __restrict__ Y, float* __restrict__ obuf,
    float* __restrict__ stats)
{
    __shared__ float sM[7 * 1024];
    __shared__ float sh[32 * kC];
    __shared__ float scb[kC];
    int t = threadIdx.x;
    if (blockIdx.x == 0 && t < 64) stats[t] = 0.f;   // zero BN stats for this layer
    for (int i = t; i < 5 * 1024; i += 256) sM[i] = W2[i];
    for (int i = t; i < 1024; i += 256) {
        sM[5 * 1024 + i] = b2[i];
        sM[6 * 1024 + i] = rootW[i];
    }
    if (t < kC) scb[t] = convb[t];

    int base = blockIdx.x * 32;
    #pragma unroll
    for (int j = 0; j < 4; ++j) {
        int idx = t + j * 256;
        int n = base + (idx >> 5);
        sh[idx] = (n < kN) ? h[n * kC + (idx & 31)] : 0.f;
    }
    __syncthreads();

    int d = t & 31;
    int li = t >> 5;   // node sub-group 0..7, nodes li*4 .. li*4+3
    float acc[7][4];
    #pragma unroll
    for (int k = 0; k < 7; ++k)
        #pragma unroll
        for (int j = 0; j < 4; ++j) acc[k][j] = 0.f;

    #pragma unroll 4
    for (int c = 0; c < kC; ++c) {
        int off = c * 32 + d;
        float m0 = sM[0 * 1024 + off];
        float m1 = sM[1 * 1024 + off];
        float m2 = sM[2 * 1024 + off];
        float m3 = sM[3 * 1024 + off];
        float m4 = sM[4 * 1024 + off];
        float m5 = sM[5 * 1024 + off];
        float m6 = sM[6 * 1024 + off];
        #pragma unroll
        for (int j = 0; j < 4; ++j) {
            float hc = sh[(li * 4 + j) * kC + c];
            acc[0][j] = fmaf(hc, m0, acc[0][j]);
            acc[1][j] = fmaf(hc, m1, acc[1][j]);
            acc[2][j] = fmaf(hc, m2, acc[2][j]);
            acc[3][j] = fmaf(hc, m3, acc[3][j]);
            acc[4][j] = fmaf(hc, m4, acc[4][j]);
            acc[5][j] = fmaf(hc, m5, acc[5][j]);
            acc[6][j] = fmaf(hc, m6, acc[6][j]);
        }
    }
    #pragma unroll
    for (int j = 0; j < 4; ++j) {
        int n = base + li * 4 + j;
        if (n >= kN) continue;
        float* yr = Y + (size_t)n * 192;
        yr[0 * 32 + d] = acc[0][j];
        yr[1 * 32 + d] = acc[1][j];
        yr[2 * 32 + d] = acc[2][j];
        yr[3 * 32 + d] = acc[3][j];
        yr[4 * 32 + d] = acc[4][j];
        yr[5 * 32 + d] = acc[5][j];
        obuf[n * kC + d] = acc[6][j] + scb[d];
    }
}

// Per edge: hid = relu(ea@W1+b1) (5 vals, lanes 0..4 of each 32-lane group),
// msg = Y[src][5] + sum_k hid_k * Y[src][k], atomicAdd into obuf[dst].
__global__ __launch_bounds__(256) void edge_msg(
    const int* __restrict__ ei_src, const int* __restrict__ ei_dst,
    const float* __restrict__ ea,
    const float* __restrict__ W1, const float* __restrict__ b1,
    const float* __restrict__ Y, float* __restrict__ obuf)
{
    __shared__ float sW1[kED * kH];
    __shared__ float sb1[kH];
    int t = threadIdx.x;
    if (t < kED * kH) sW1[t] = W1[t];
    if (t < kH) sb1[t] = b1[t];
    __syncthreads();
    int gid = blockIdx.x * 256 + t;
    int e = gid >> 5;
    int d = gid & 31;
    if (e >= kE) return;
    int src = ei_src[e];
    int dst = ei_dst[e];
    float hv = 0.f;
    if (d < kH) {
        const float* er = ea + e * kED;
        float a = sb1[d];
        #pragma unroll
        for (int j = 0; j < kED; ++j) a = fmaf(er[j], sW1[j * kH + d], a);
        hv = a > 0.f ? a : 0.f;
    }
    float h0 = __shfl(hv, 0, 32);
    float h1 = __shfl(hv, 1, 32);
    float h2 = __shfl(hv, 2, 32);
    float h3 = __shfl(hv, 3, 32);
    float h4 = __shfl(hv, 4, 32);
    const float* yr = Y + (size_t)src * 192;
    float m = yr[5 * 32 + d];
    m = fmaf(h0, yr[0 * 32 + d], m);
    m = fmaf(h1, yr[1 * 32 + d], m);
    m = fmaf(h2, yr[2 * 32 + d], m);
    m = fmaf(h3, yr[3 * 32 + d], m);
    m = fmaf(h4, yr[4 * 32 + d], m);
    atomicAdd(&obuf[dst * kC + d], m);
}

// Per-channel sum & sumsq over all N nodes -> stats[0..31]=sum, [32..63]=sumsq
__global__ __launch_bounds__(256) void bn_reduce(
    const float* __restrict__ obuf, float* __restrict__ stats)
{
    __shared__ float ls[256];
    __shared__ float lq[256];
    int t = threadIdx.x;
    int c = t & 31;
    int row = t >> 5;
    float s = 0.f, q = 0.f;
    for (int n = blockIdx.x * 8 + row; n < kN; n += gridDim.x * 8) {
        float v = obuf[n * kC + c];
        s += v; q += v * v;
    }
    ls[t] = s; lq[t] = q;
    __syncthreads();
    if (t < 128) { ls[t] += ls[t + 128]; lq[t] += lq[t + 128]; }
    __syncthreads();
    if (t < 64) { ls[t] += ls[t + 64]; lq[t] += lq[t + 64]; }
    __syncthreads();
    if (t < 32) {
        atomicAdd(&stats[t], ls[t] + ls[t + 32]);
        atomicAdd(&stats[32 + t], lq[t] + lq[t + 32]);
    }
}

// Intermediate layers: normalize + leaky into h.
__global__ __launch_bounds__(256) void bn_norm_mid(
    const float* __restrict__ obuf, const float* __restrict__ stats,
    const float* __restrict__ g, const float* __restrict__ b,
    float* __restrict__ h)
{
    int idx = blockIdx.x * 256 + threadIdx.x;
    if (idx >= kN * kC) return;
    int c = idx & 31;
    float mu = stats[c] * (1.f / kN);
    float var = stats[32 + c] * (1.f / kN) - mu * mu;
    float inv = rsqrtf(var + kEps);
    float v = (obuf[idx] - mu) * inv * g[c] + b[c];
    h[idx] = v > 0.f ? v : 0.01f * v;
}

// Final layer: normalize (no leaky), fused per-node prediction dot
// v[n] = h[n] . pred_W  (32-lane shuffle reduce), init out[] with pred_b.
__global__ __launch_bounds__(256) void bn_norm_final(
    const float* __restrict__ obuf, const float* __restrict__ stats,
    const float* __restrict__ g, const float* __restrict__ b,
    float* __restrict__ h, float* __restrict__ vbuf,
    const float* __restrict__ predW,
    float* __restrict__ out, const float* __restrict__ pred_b)
{
    int idx = blockIdx.x * 256 + threadIdx.x;
    if (idx < kG) out[idx] = pred_b[0];
    if (idx >= kN * kC) return;
    int c = idx & 31;
    float mu = stats[c] * (1.f / kN);
    float var = stats[32 + c] * (1.f / kN) - mu * mu;
    float inv = rsqrtf(var + kEps);
    float v = (obuf[idx] - mu) * inv * g[c] + b[c];
    h[idx] = v;
    float pv = v * predW[c];
    #pragma unroll
    for (int off = 16; off > 0; off >>= 1) pv += __shfl_down(pv, off, 32);
    if (c == 0) vbuf[idx >> 5] = pv;
}

// Segment-sum of per-node scalars v[n] into out[batch[n]], exploiting sorted
// batch ids: register runs -> 500-entry LDS accumulator -> ~#graphs-per-block
// global atomics (instead of 50K clustered same-address atomics).
__global__ __launch_bounds__(256) void seg_readout(
    const float* __restrict__ vbuf, const int* __restrict__ batch,
    float* __restrict__ out)
{
    __shared__ float ls[kG];
    int t = threadIdx.x;
    for (int i = t; i < kG; i += 256) ls[i] = 0.f;
    __syncthreads();
    int base = blockIdx.x * 2048 + t * 8;
    int cur = -1;
    float acc = 0.f;
    #pragma unroll
    for (int i = 0; i < 8; ++i) {
        int n = base + i;
        if (n >= kN) break;
        int gidx = batch[n];
        float val = vbuf[n];
        if (gidx != cur) {
            if (cur >= 0) atomicAdd(&ls[cur], acc);
            cur = gidx;
            acc = val;
        } else {
            acc += val;
        }
    }
    if (cur >= 0) atomicAdd(&ls[cur], acc);
    __syncthreads();
    for (int gidx = t; gidx < kG; gidx += 256) {
        float s = ls[gidx];
        if (s != 0.f) atomicAdd(&out[gidx], s);
    }
}

} // namespace

extern "C" void kernel_launch(void* const* d_in, const int* in_sizes, int n_in,
                              void* d_out, int out_size, void* d_ws, size_t ws_size,
                              hipStream_t stream)
{
    const float* x      = (const float*)d_in[0];
    const int*   ei     = (const int*)d_in[1];
    const float* ea     = (const float*)d_in[2];
    const int*   batch  = (const int*)d_in[3];
    const float* lin_W  = (const float*)d_in[4];
    const float* lin_b  = (const float*)d_in[5];
    const float* mes_W1 = (const float*)d_in[6];
    const float* mes_b1 = (const float*)d_in[7];
    const float* mes_W2 = (const float*)d_in[8];
    const float* mes_b2 = (const float*)d_in[9];
    const float* root_W = (const float*)d_in[10];
    const float* conv_b = (const float*)d_in[11];
    const float* bn_g   = (const float*)d_in[12];
    const float* bn_b   = (const float*)d_in[13];
    const float* pred_W = (const float*)d_in[14];
    const float* pred_b = (const float*)d_in[15];
    float* out = (float*)d_out;

    // workspace layout (floats): hbuf[N*C] | obuf[N*C] | Y[N*6*C] | stats[64]
    // vbuf[N] overlays Y (Y is dead after the last edge_msg).
    float* hbuf  = (float*)d_ws;
    float* obuf  = hbuf + (size_t)kN * kC;
    float* Y     = obuf + (size_t)kN * kC;
    float* stats = Y + (size_t)kN * 6 * kC;
    float* vbuf  = Y;

    init_h<<<(kN + 7) / 8, 256, 0, stream>>>(x, lin_W, lin_b, hbuf);

    int nb = (kN * kC + 255) / 256;
    for (int l = 0; l < kL; ++l) {
        y_root<<<(kN + 31) / 32, 256, 0, stream>>>(
            hbuf, mes_W2 + l * kH * kC * kC, mes_b2 + l * kC * kC,
            root_W + l * kC * kC, conv_b + l * kC, Y, obuf, stats);
        edge_msg<<<(kE * 32 + 255) / 256, 256, 0, stream>>>(
            ei, ei + kE, ea, mes_W1 + l * kED * kH, mes_b1 + l * kH, Y, obuf);
        bn_reduce<<<512, 256, 0, stream>>>(obuf, stats);
        if (l < kL - 1)
            bn_norm_mid<<<nb, 256, 0, stream>>>(
                obuf, stats, bn_g + l * kC, bn_b + l * kC, hbuf);
        else
            bn_norm_final<<<nb, 256, 0, stream>>>(
                obuf, stats, bn_g + l * kC, bn_b + l * kC, hbuf, vbuf,
                pred_W, out, pred_b);
    }

    seg_readout<<<(kN + 2047) / 2048, 256, 0, stream>>>(vbuf, batch, out);
}

// Round 3
// 340.695 us; speedup vs baseline: 1.1991x; 1.0070x over previous
//
#include <hip/hip_runtime.h>

namespace {

constexpr int kN  = 50000;
constexpr int kE  = 200000;
constexpr int kC  = 32;
constexpr int kND = 75;
constexpr int kED = 12;
constexpr int kL  = 3;
constexpr int kG  = 500;
constexpr int kH  = 5;
constexpr float kEps = 1e-5f;

__device__ __forceinline__ unsigned bf16rn(float x) {
    unsigned u = __float_as_uint(x);
    return (u + 0x7FFFu + ((u >> 16) & 1u)) >> 16;   // round-to-nearest-even bf16
}
__device__ __forceinline__ float bf16lo(unsigned p) { return __uint_as_float(p << 16); }
__device__ __forceinline__ float bf16hi(unsigned p) { return __uint_as_float(p & 0xFFFF0000u); }

// h = leaky(x @ lin_W + lin_b)   [N,75]@[75,32]
__global__ __launch_bounds__(256) void init_h(
    const float* __restrict__ x, const float* __restrict__ W,
    const float* __restrict__ b, float* __restrict__ h)
{
    __shared__ float sW[kND * kC];
    __shared__ float sb[kC];
    int t = threadIdx.x;
    for (int i = t; i < kND * kC; i += 256) sW[i] = W[i];
    if (t < kC) sb[t] = b[t];
    __syncthreads();
    int c = t & 31;
    int n = blockIdx.x * 8 + (t >> 5);
    if (n >= kN) return;
    const float* xr = x + n * kND;
    float acc = sb[c];
    #pragma unroll 5
    for (int f = 0; f < kND; ++f) acc = fmaf(xr[f], sW[f * kC + c], acc);
    h[n * kC + c] = acc > 0.f ? acc : 0.01f * acc;
}

// Per node: Y[n][d][k] (bf16, k=0..4 -> h@M_k, k=5 -> h@B2mat),
// obuf[n][:] = h[n] @ rootW + conv_b (fp32).  Block = 32 nodes, 4/thread.
__global__ __launch_bounds__(256) void y_root(
    const float* __restrict__ h,
    const float* __restrict__ W2,    // [5*1024] this layer
    const float* __restrict__ b2,    // [1024]
    const float* __restrict__ rootW, // [1024]
    const float* __restrict__ convb, // [32]
    unsigned short* __restrict__ Y, float* __restrict__ obuf,
    float* __restrict__ stats)
{
    __shared__ float sM[7 * 1024];
    __shared__ float sh[32 * kC];
    __shared__ float scb[kC];
    int t = threadIdx.x;
    if (blockIdx.x == 0 && t < 64) stats[t] = 0.f;   // zero BN stats for this layer
    for (int i = t; i < 5 * 1024; i += 256) sM[i] = W2[i];
    for (int i = t; i < 1024; i += 256) {
        sM[5 * 1024 + i] = b2[i];
        sM[6 * 1024 + i] = rootW[i];
    }
    if (t < kC) scb[t] = convb[t];

    int base = blockIdx.x * 32;
    #pragma unroll
    for (int j = 0; j < 4; ++j) {
        int idx = t + j * 256;
        int n = base + (idx >> 5);
        sh[idx] = (n < kN) ? h[n * kC + (idx & 31)] : 0.f;
    }
    __syncthreads();

    int d = t & 31;
    int li = t >> 5;   // node sub-group 0..7, nodes li*4 .. li*4+3
    float acc[7][4];
    #pragma unroll
    for (int k = 0; k < 7; ++k)
        #pragma unroll
        for (int j = 0; j < 4; ++j) acc[k][j] = 0.f;

    #pragma unroll 4
    for (int c = 0; c < kC; ++c) {
        int off = c * 32 + d;
        float m0 = sM[0 * 1024 + off];
        float m1 = sM[1 * 1024 + off];
        float m2 = sM[2 * 1024 + off];
        float m3 = sM[3 * 1024 + off];
        float m4 = sM[4 * 1024 + off];
        float m5 = sM[5 * 1024 + off];
        float m6 = sM[6 * 1024 + off];
        #pragma unroll
        for (int j = 0; j < 4; ++j) {
            float hc = sh[(li * 4 + j) * kC + c];
            acc[0][j] = fmaf(hc, m0, acc[0][j]);
            acc[1][j] = fmaf(hc, m1, acc[1][j]);
            acc[2][j] = fmaf(hc, m2, acc[2][j]);
            acc[3][j] = fmaf(hc, m3, acc[3][j]);
            acc[4][j] = fmaf(hc, m4, acc[4][j]);
            acc[5][j] = fmaf(hc, m5, acc[5][j]);
            acc[6][j] = fmaf(hc, m6, acc[6][j]);
        }
    }
    #pragma unroll
    for (int j = 0; j < 4; ++j) {
        int n = base + li * 4 + j;
        if (n >= kN) continue;
        // pack 6 bf16 (k0..k5) into 3 dwords at Y + n*192 + d*6 (byte ofs n*384+d*12)
        unsigned* yr = (unsigned*)(Y + (size_t)n * 192 + d * 6);
        yr[0] = bf16rn(acc[0][j]) | (bf16rn(acc[1][j]) << 16);
        yr[1] = bf16rn(acc[2][j]) | (bf16rn(acc[3][j]) << 16);
        yr[2] = bf16rn(acc[4][j]) | (bf16rn(acc[5][j]) << 16);
        obuf[n * kC + d] = acc[6][j] + scb[d];
    }
}

// Per edge: hid = relu(ea@W1+b1) (lanes 0..4 of each 32-lane group),
// msg = Y[src][.][5] + sum_k hid_k * Y[src][.][k], atomicAdd into obuf[dst].
// Y gather: 3 dwords/lane, 3 cachelines/edge (bf16-packed).
__global__ __launch_bounds__(256) void edge_msg(
    const int* __restrict__ ei_src, const int* __restrict__ ei_dst,
    const float* __restrict__ ea,
    const float* __restrict__ W1, const float* __restrict__ b1,
    const unsigned short* __restrict__ Y, float* __restrict__ obuf)
{
    __shared__ float sW1[kED * kH];
    __shared__ float sb1[kH];
    int t = threadIdx.x;
    if (t < kED * kH) sW1[t] = W1[t];
    if (t < kH) sb1[t] = b1[t];
    __syncthreads();
    int gid = blockIdx.x * 256 + t;
    int e = gid >> 5;
    int d = gid & 31;
    if (e >= kE) return;
    int src = ei_src[e];
    int dst = ei_dst[e];
    float hv = 0.f;
    if (d < kH) {
        const float* er = ea + e * kED;
        float a = sb1[d];
        #pragma unroll
        for (int j = 0; j < kED; ++j) a = fmaf(er[j], sW1[j * kH + d], a);
        hv = a > 0.f ? a : 0.f;
    }
    float h0 = __shfl(hv, 0, 32);
    float h1 = __shfl(hv, 1, 32);
    float h2 = __shfl(hv, 2, 32);
    float h3 = __shfl(hv, 3, 32);
    float h4 = __shfl(hv, 4, 32);
    const unsigned* yr = (const unsigned*)(Y + (size_t)src * 192 + d * 6);
    unsigned p0 = yr[0];
    unsigned p1 = yr[1];
    unsigned p2 = yr[2];
    float m = bf16hi(p2);                 // k5: bias-matrix term
    m = fmaf(h0, bf16lo(p0), m);
    m = fmaf(h1, bf16hi(p0), m);
    m = fmaf(h2, bf16lo(p1), m);
    m = fmaf(h3, bf16hi(p1), m);
    m = fmaf(h4, bf16lo(p2), m);
    atomicAdd(&obuf[dst * kC + d], m);
}

// Per-channel sum & sumsq over all N nodes -> stats[0..31]=sum, [32..63]=sumsq
__global__ __launch_bounds__(256) void bn_reduce(
    const float* __restrict__ obuf, float* __restrict__ stats)
{
    __shared__ float ls[256];
    __shared__ float lq[256];
    int t = threadIdx.x;
    int c = t & 31;
    int row = t >> 5;
    float s = 0.f, q = 0.f;
    for (int n = blockIdx.x * 8 + row; n < kN; n += gridDim.x * 8) {
        float v = obuf[n * kC + c];
        s += v; q += v * v;
    }
    ls[t] = s; lq[t] = q;
    __syncthreads();
    if (t < 128) { ls[t] += ls[t + 128]; lq[t] += lq[t + 128]; }
    __syncthreads();
    if (t < 64) { ls[t] += ls[t + 64]; lq[t] += lq[t + 64]; }
    __syncthreads();
    if (t < 32) {
        atomicAdd(&stats[t], ls[t] + ls[t + 32]);
        atomicAdd(&stats[32 + t], lq[t] + lq[t + 32]);
    }
}

// Intermediate layers: normalize + leaky into h.
__global__ __launch_bounds__(256) void bn_norm_mid(
    const float* __restrict__ obuf, const float* __restrict__ stats,
    const float* __restrict__ g, const float* __restrict__ b,
    float* __restrict__ h)
{
    int idx = blockIdx.x * 256 + threadIdx.x;
    if (idx >= kN * kC) return;
    int c = idx & 31;
    float mu = stats[c] * (1.f / kN);
    float var = stats[32 + c] * (1.f / kN) - mu * mu;
    float inv = rsqrtf(var + kEps);
    float v = (obuf[idx] - mu) * inv * g[c] + b[c];
    h[idx] = v > 0.f ? v : 0.01f * v;
}

// Final layer: normalize (no leaky), fused per-node prediction dot
// v[n] = h[n] . pred_W  (32-lane shuffle reduce), init out[] with pred_b.
__global__ __launch_bounds__(256) void bn_norm_final(
    const float* __restrict__ obuf, const float* __restrict__ stats,
    const float* __restrict__ g, const float* __restrict__ b,
    float* __restrict__ vbuf,
    const float* __restrict__ predW,
    float* __restrict__ out, const float* __restrict__ pred_b)
{
    int idx = blockIdx.x * 256 + threadIdx.x;
    if (idx < kG) out[idx] = pred_b[0];
    if (idx >= kN * kC) return;
    int c = idx & 31;
    float mu = stats[c] * (1.f / kN);
    float var = stats[32 + c] * (1.f / kN) - mu * mu;
    float inv = rsqrtf(var + kEps);
    float v = (obuf[idx] - mu) * inv * g[c] + b[c];
    float pv = v * predW[c];
    #pragma unroll
    for (int off = 16; off > 0; off >>= 1) pv += __shfl_down(pv, off, 32);
    if (c == 0) vbuf[idx >> 5] = pv;
}

// Segment-sum of per-node scalars v[n] into out[batch[n]], exploiting sorted
// batch ids: register runs -> 500-entry LDS accumulator -> few global atomics.
__global__ __launch_bounds__(256) void seg_readout(
    const float* __restrict__ vbuf, const int* __restrict__ batch,
    float* __restrict__ out)
{
    __shared__ float ls[kG];
    int t = threadIdx.x;
    for (int i = t; i < kG; i += 256) ls[i] = 0.f;
    __syncthreads();
    int base = blockIdx.x * 2048 + t * 8;
    int cur = -1;
    float acc = 0.f;
    #pragma unroll
    for (int i = 0; i < 8; ++i) {
        int n = base + i;
        if (n >= kN) break;
        int gidx = batch[n];
        float val = vbuf[n];
        if (gidx != cur) {
            if (cur >= 0) atomicAdd(&ls[cur], acc);
            cur = gidx;
            acc = val;
        } else {
            acc += val;
        }
    }
    if (cur >= 0) atomicAdd(&ls[cur], acc);
    __syncthreads();
    for (int gidx = t; gidx < kG; gidx += 256) {
        float s = ls[gidx];
        if (s != 0.f) atomicAdd(&out[gidx], s);
    }
}

} // namespace

extern "C" void kernel_launch(void* const* d_in, const int* in_sizes, int n_in,
                              void* d_out, int out_size, void* d_ws, size_t ws_size,
                              hipStream_t stream)
{
    const float* x      = (const float*)d_in[0];
    const int*   ei     = (const int*)d_in[1];
    const float* ea     = (const float*)d_in[2];
    const int*   batch  = (const int*)d_in[3];
    const float* lin_W  = (const float*)d_in[4];
    const float* lin_b  = (const float*)d_in[5];
    const float* mes_W1 = (const float*)d_in[6];
    const float* mes_b1 = (const float*)d_in[7];
    const float* mes_W2 = (const float*)d_in[8];
    const float* mes_b2 = (const float*)d_in[9];
    const float* root_W = (const float*)d_in[10];
    const float* conv_b = (const float*)d_in[11];
    const float* bn_g   = (const float*)d_in[12];
    const float* bn_b   = (const float*)d_in[13];
    const float* pred_W = (const float*)d_in[14];
    const float* pred_b = (const float*)d_in[15];
    float* out = (float*)d_out;

    // workspace (floats): hbuf[N*C] | obuf[N*C] | Ybf16[N*192 ushort = N*96 f32] | stats[64]
    // vbuf[N] overlays the Y region (Y dead after last edge_msg).
    float* hbuf  = (float*)d_ws;
    float* obuf  = hbuf + (size_t)kN * kC;
    unsigned short* Y = (unsigned short*)(obuf + (size_t)kN * kC);
    float* stats = (float*)(Y + (size_t)kN * 192);
    float* vbuf  = (float*)Y;

    init_h<<<(kN + 7) / 8, 256, 0, stream>>>(x, lin_W, lin_b, hbuf);

    int nb = (kN * kC + 255) / 256;
    for (int l = 0; l < kL; ++l) {
        y_root<<<(kN + 31) / 32, 256, 0, stream>>>(
            hbuf, mes_W2 + l * kH * kC * kC, mes_b2 + l * kC * kC,
            root_W + l * kC * kC, conv_b + l * kC, Y, obuf, stats);
        edge_msg<<<(kE * 32 + 255) / 256, 256, 0, stream>>>(
            ei, ei + kE, ea, mes_W1 + l * kED * kH, mes_b1 + l * kH, Y, obuf);
        bn_reduce<<<512, 256, 0, stream>>>(obuf, stats);
        if (l < kL - 1)
            bn_norm_mid<<<nb, 256, 0, stream>>>(
                obuf, stats, bn_g + l * kC, bn_b + l * kC, hbuf);
        else
            bn_norm_final<<<nb, 256, 0, stream>>>(
                obuf, stats, bn_g + l * kC, bn_b + l * kC, vbuf,
                pred_W, out, pred_b);
    }

    seg_readout<<<(kN + 2047) / 2048, 256, 0, stream>>>(vbuf, batch, out);
}